// Round 13
// baseline (217.745 us; speedup 1.0000x reference)
//
#include <hip/hip_runtime.h>
#include <hip/hip_bf16.h>
#include <math.h>

#define N_NODES  20000
#define N_EDGES  256000
#define E_TOT    276000      // + self loops
#define N_GRAPHS 512
#define F_IN     75
#define HEADS    10
#define D1       750         // HEADS*F_IN
#define XK       80          // x cols padded (per-head k for layer1)
#define XKP      96          // MFMA K-pad for per-head GEMM
#define HOUT     80          // padded per-head output cols (75 real)
#define D2P      800         // 10*80 : gemm2m K
#define OUT_DIM  128
#define NPAD     20096       // 314 * 64
#define CAP      96          // per-node edge bucket capacity (Poisson(13.8): P(>96)~0)

typedef __attribute__((ext_vector_type(8))) short bf16x8;
typedef __attribute__((ext_vector_type(8))) unsigned short u16x8;
typedef __attribute__((ext_vector_type(4))) float f32x4;

__device__ __forceinline__ unsigned short f2bf(float v) {
    unsigned int u = __float_as_uint(v);
    u += 0x7fffu + ((u >> 16) & 1u);       // RNE
    return (unsigned short)(u >> 16);
}
__device__ __forceinline__ float bf2f(unsigned short u) {
    return __uint_as_float(((unsigned int)u) << 16);
}

// ---------------- merged prep: va + casts + zeroing (1 dispatch) ----------------
#define PS1 (20*F_IN)
#define PS2 (PS1 + N_NODES*XK)
#define PS3 (PS2 + HEADS*HOUT*XKP)
#define PS4 (PS3 + OUT_DIM*D2P)
#define PS5 (PS4 + N_NODES)
#define PS6 (PS5 + N_GRAPHS*OUT_DIM)

__global__ __launch_bounds__(256) void k_prep(const float* __restrict__ x,
                                              const float* __restrict__ W1,
                                              const float* __restrict__ a_s,
                                              const float* __restrict__ a_d,
                                              const float* __restrict__ W2,
                                              float* __restrict__ va,
                                              unsigned short* __restrict__ xbp,
                                              unsigned short* __restrict__ w1bh,
                                              unsigned short* __restrict__ w2t,
                                              int* __restrict__ cnt,
                                              float* __restrict__ g) {
    int id = blockIdx.x*256 + threadIdx.x;
    if (id < PS1) {                                     // va[p][k]
        int p = id / F_IN, k = id - p*F_IN;
        int h = (p < HEADS) ? p : p - HEADS;
        const float* avec = (p < HEADS) ? (a_s + h*F_IN) : (a_d + h*F_IN);
        float s = 0.f;
        for (int f=0; f<F_IN; f++) s += avec[f] * W1[(size_t)k*D1 + h*F_IN + f];
        va[id] = s;
    } else if (id < PS2) {                              // xbp
        int i = id - PS1;
        int r = i / XK, c = i - r*XK;
        xbp[i] = (c < F_IN) ? f2bf(x[(size_t)r*F_IN + c]) : 0;
    } else if (id < PS3) {                              // w1bh[h][j][k]
        int i = id - PS2;
        int h = i / (HOUT*XKP);
        int r = i - h*(HOUT*XKP);
        int j = r / XKP, k = r - j*XKP;
        w1bh[i] = (j < F_IN && k < F_IN) ? f2bf(W1[(size_t)k*D1 + h*F_IN + j]) : 0;
    } else if (id < PS4) {                              // w2t[j][h*80+kk]
        int i = id - PS3;
        int j = i / D2P, c = i - j*D2P;
        int h = c / HOUT, kk = c - h*HOUT;
        w2t[i] = (kk < F_IN) ? f2bf(W2[(size_t)(h*F_IN+kk)*OUT_DIM + j]) : 0;
    } else if (id < PS5) {                              // zero cnt
        cnt[id - PS4] = 0;
    } else if (id < PS6) {                              // zero g
        g[id - PS5] = 0.f;
    }
}

// ---------------- bucket scatter + alpha1 (merged, one dispatch) ----------------
#define SCAT_BLOCKS ((E_TOT+255)/256)
#define ALPHA_BLOCKS ((N_NODES*20+255)/256)
__global__ __launch_bounds__(256) void k_scat_alpha(const int* __restrict__ ei,
                                                    int* __restrict__ cnt, int* __restrict__ bucket,
                                                    const float* __restrict__ x, const float* __restrict__ va,
                                                    float* __restrict__ aso, float* __restrict__ ado) {
    if (blockIdx.x < SCAT_BLOCKS) {
        int e = blockIdx.x*256 + threadIdx.x;
        if (e >= E_TOT) return;
        int s, d;
        if (e < N_EDGES) { s = ei[e]; d = ei[N_EDGES+e]; }
        else             { s = e - N_EDGES; d = s; }
        int pos = atomicAdd(&cnt[d], 1);
        if (pos < CAP) bucket[(size_t)d*CAP + pos] = s;
    } else {
        int at = ((int)blockIdx.x - SCAT_BLOCKS)*256 + (int)threadIdx.x;
        if (at >= N_NODES*20) return;
        int n = at / 20, p = at - n*20;
        const float* xr = x  + (size_t)n*F_IN;
        const float* vr = va + p*F_IN;
        float s = 0.f;
        #pragma unroll 5
        for (int k=0;k<F_IN;k++) s += xr[k]*vr[k];
        if (p < HEADS) aso[n*HEADS + p] = s;
        else           ado[n*HEADS + (p-HEADS)] = s;
    }
}

// ---------------- fused layer-1 edge softmax + aggregation ----------------
// CH1=24 with dual e-slots per thread (halves barrier rounds for deg<=24).
#define CH1 24
__global__ __launch_bounds__(128) void k_fagg1(const unsigned short* __restrict__ xbp,
                                               const float* __restrict__ aso,
                                               const float* __restrict__ ado,
                                               const int* __restrict__ cnt,
                                               const int* __restrict__ bucket,
                                               unsigned short* __restrict__ xaggb) {
    int n = blockIdx.x, t = threadIdx.x;
    __shared__ float els[CH1][HEADS];
    int deg = min(cnt[n], CAP);
    const int* brow = bucket + (size_t)n*CAP;
    if (t >= 100 && t < 120) {            // zero k-pad cols 80..95, all heads
        int hh = (t-100) >> 1, half = (t-100) & 1;
        *(u16x8*)(xaggb + (size_t)n*960 + hh*XKP + XK + half*8) = (u16x8){0,0,0,0,0,0,0,0};
    }
    const int h1 = t % 10, u1 = t / 10;   // phase-1 role (t<120): slots u1, u1+12
    const float adn1 = (t < 120) ? ado[(size_t)n*HEADS + h1] : 0.f;
    const int h2 = t / 10, k8 = (t - h2*10) * 8;  // phase-2 role (t<100)
    float acc[8] = {0,0,0,0,0,0,0,0};
    float den = 0.f;

    for (int base = 0; base < deg; base += CH1) {
        int m = min(CH1, deg - base);
        if (t < 120) {
            if (u1 < m) {
                int src = brow[base + u1];
                float v = aso[(size_t)src*HEADS + h1] + adn1;
                v = v > 0.f ? v : 0.2f*v;
                els[u1][h1] = __expf(v);
            }
            int u2 = u1 + 12;
            if (u2 < m) {
                int src = brow[base + u2];
                float v = aso[(size_t)src*HEADS + h1] + adn1;
                v = v > 0.f ? v : 0.2f*v;
                els[u2][h1] = __expf(v);
            }
        }
        __syncthreads();
        if (t < 100) {
            int u = 0;
            for (; u + 4 <= m; u += 4) {
                int sA = brow[base+u], sB = brow[base+u+1], sC = brow[base+u+2], sD = brow[base+u+3];
                float eA = els[u][h2], eB = els[u+1][h2], eC = els[u+2][h2], eD = els[u+3][h2];
                u16x8 xA = *(const u16x8*)(xbp + (size_t)sA*XK + k8);
                u16x8 xB = *(const u16x8*)(xbp + (size_t)sB*XK + k8);
                u16x8 xC = *(const u16x8*)(xbp + (size_t)sC*XK + k8);
                u16x8 xD = *(const u16x8*)(xbp + (size_t)sD*XK + k8);
                den += eA + eB + eC + eD;
                #pragma unroll
                for (int c=0;c<8;c++)
                    acc[c] += bf2f(xA[c])*eA + bf2f(xB[c])*eB + bf2f(xC[c])*eC + bf2f(xD[c])*eD;
            }
            for (; u < m; u++) {
                int src = brow[base+u];
                float e = els[u][h2];
                den += e;
                u16x8 xv = *(const u16x8*)(xbp + (size_t)src*XK + k8);
                #pragma unroll
                for (int c=0;c<8;c++) acc[c] += bf2f(xv[c]) * e;
            }
        }
        __syncthreads();
    }
    if (t < 100) {
        float iv = 1.f / (den + 1e-16f);
        u16x8 ov;
        #pragma unroll
        for (int c=0;c<8;c++) ov[c] = f2bf(acc[c] * iv);
        *(u16x8*)(xaggb + (size_t)n*960 + h2*XKP + k8) = ov;
    }
}

// ---------------- MFMA GEMMs ----------------

#define GLD16(g, s) __builtin_amdgcn_global_load_lds( \
    (const __attribute__((address_space(1))) void*)(g), \
    (__attribute__((address_space(3))) void*)(s), 16, 0, 0)

// h1act[:, h*80..] = ELU( xagg_h @ w1bh[h] + b1_h ) ; per-head GEMM [NPAD x 96] @ [96 x 80]
__global__ __launch_bounds__(256) void k_gemmh(const unsigned short* __restrict__ A,   // xaggb [NPAD][10][96]
                                               const unsigned short* __restrict__ B,   // w1bh [10][80][96]
                                               const float* __restrict__ b1,
                                               unsigned short* __restrict__ h1act) {   // [NPAD][800]
    __shared__ char lds[2][9216];   // A 64x32 bf16 (4KB) + B 80x32 bf16 (5KB)
    const int t = threadIdx.x, l = t & 63, w = t >> 6;
    const int n0 = blockIdx.x * 64;
    const int h  = blockIdx.y;
    const unsigned short* Ah = A + (size_t)h*XKP;
    const unsigned short* Bh = B + (size_t)h*HOUT*XKP;

    const int arow  = t >> 2;
    const int aslot = (t & 3) ^ ((t >> 3) & 3);

    f32x4 acc[5];
    #pragma unroll
    for (int n=0;n<5;n++) acc[n] = (f32x4){0.f,0.f,0.f,0.f};

    auto stage = [&](int ks, int buf) {
        const int k0 = ks * 32;
        GLD16(Ah + (size_t)(n0 + arow)*960 + k0 + aslot*8, lds[buf] + t*16);
        GLD16(Bh + (size_t)arow*XKP        + k0 + aslot*8, lds[buf] + 4096 + t*16);
        if (t < 64)
            GLD16(Bh + (size_t)(64 + arow)*XKP + k0 + aslot*8, lds[buf] + 8192 + t*16);
    };

    const int fr = l & 15;
    const int fs = ((l >> 4) ^ ((fr >> 1) & 3));
    const int abyte = (w*16 + fr)*64 + fs*16;

    stage(0, 0);
    int cb = 0;
    for (int ks = 0; ks < 3; ks++) {
        __syncthreads();
        if (ks + 1 < 3) stage(ks+1, cb^1);
        const char* Ab = lds[cb];
        const char* Bb = lds[cb] + 4096;
        bf16x8 af = *(const bf16x8*)(Ab + abyte);
        bf16x8 bfr[5];
        #pragma unroll
        for (int n=0;n<5;n++) bfr[n] = *(const bf16x8*)(Bb + (n*16 + fr)*64 + fs*16);
        #pragma unroll
        for (int n=0;n<5;n++)
            acc[n] = __builtin_amdgcn_mfma_f32_16x16x32_bf16(af, bfr[n], acc[n], 0, 0, 0);
        cb ^= 1;
    }

    const int rbase = n0 + w*16 + (l>>4)*4;
    #pragma unroll
    for (int n=0;n<5;n++) {
        int jp = n*16 + (l & 15);      // 0..79
        #pragma unroll
        for (int q=0;q<4;q++) {
            int node = rbase + q;
            unsigned short r = 0;
            if (jp < F_IN) {
                float v = acc[n][q] + b1[h*F_IN + jp];
                r = f2bf(v > 0.f ? v : __expf(v) - 1.f);
            }
            h1act[(size_t)node*D2P + h*HOUT + jp] = r;
        }
    }
}

// h2b(bf16) = h1act @ W2 ; fused alpha2 epilogue (fp32 acc -> aso2/ado2).
__global__ __launch_bounds__(256) void k_gemm2m(const unsigned short* __restrict__ A,
                                                const unsigned short* __restrict__ Bt,
                                                const float* __restrict__ a_s2,
                                                const float* __restrict__ a_d2,
                                                unsigned short* __restrict__ C,
                                                float* __restrict__ aso2,
                                                float* __restrict__ ado2) {
    __shared__ char lds[2][12288];
    __shared__ float sm_ps[64], sm_pd[64];
    const int t  = threadIdx.x;
    const int l  = t & 63;
    const int w  = t >> 6;
    const int wr = w >> 1, wc = w & 1;
    const int n0 = blockIdx.x * 64;

    const int arow  = t >> 2;
    const int aslot = (t & 3) ^ ((t >> 3) & 3);
    const int brow1 = arow + 64;

    f32x4 acc[2][4];
    #pragma unroll
    for (int m=0;m<2;m++)
        #pragma unroll
        for (int n=0;n<4;n++) acc[m][n] = (f32x4){0.f,0.f,0.f,0.f};

    auto stage = [&](int ks, int buf) {
        const int k0 = ks * 32;
        GLD16(A  + (size_t)(n0 + arow)*D2P + k0 + aslot*8, lds[buf] + t*16);
        GLD16(Bt + (size_t)arow       *D2P + k0 + aslot*8, lds[buf] + 4096 + t*16);
        GLD16(Bt + (size_t)brow1      *D2P + k0 + aslot*8, lds[buf] + 8192 + t*16);
    };

    const int fr   = l & 15;
    const int fs   = ((l >> 4) ^ ((fr >> 1) & 3));
    const int abyte = (wr*32 + fr)*64 + fs*16;
    const int bbyte = (wc*64 + fr)*64 + fs*16;

    stage(0, 0);
    int cb = 0;
    for (int ks = 0; ks < D2P/32; ks++) {
        __syncthreads();
        if (ks+1 < D2P/32) stage(ks+1, cb^1);
        const char* Ab = lds[cb];
        const char* Bb = lds[cb] + 4096;
        bf16x8 af[2], bfr[4];
        #pragma unroll
        for (int m=0;m<2;m++) af[m] = *(const bf16x8*)(Ab + abyte + m*1024);
        #pragma unroll
        for (int n=0;n<4;n++) bfr[n] = *(const bf16x8*)(Bb + bbyte + n*1024);
        #pragma unroll
        for (int m=0;m<2;m++)
            #pragma unroll
            for (int n=0;n<4;n++)
                acc[m][n] = __builtin_amdgcn_mfma_f32_16x16x32_bf16(af[m], bfr[n], acc[m][n], 0, 0, 0);
        cb ^= 1;
    }

    // C write (bf16)
    #pragma unroll
    for (int m=0;m<2;m++) {
        int rbase = n0 + wr*32 + m*16 + (l>>4)*4;
        #pragma unroll
        for (int n=0;n<4;n++) {
            int col = wc*64 + n*16 + (l&15);
            #pragma unroll
            for (int q=0;q<4;q++) {
                int node = rbase + q;
                if (node < N_NODES) C[(size_t)node*OUT_DIM + col] = f2bf(acc[m][n][q]);
            }
        }
    }

    // fused alpha2: ps[r]=sum_col h2[r,col]*a_s2[col], pd likewise (fp32 acc)
    float av[4], bv[4];
    #pragma unroll
    for (int n=0;n<4;n++) {
        int col = wc*64 + n*16 + (l&15);
        av[n] = a_s2[col];
        bv[n] = a_d2[col];
    }
    float psv[8], pdv[8];
    #pragma unroll
    for (int m=0;m<2;m++) {
        #pragma unroll
        for (int q=0;q<4;q++) {
            float ps = 0.f, pd = 0.f;
            #pragma unroll
            for (int n=0;n<4;n++) { ps += acc[m][n][q]*av[n]; pd += acc[m][n][q]*bv[n]; }
            #pragma unroll
            for (int o=8;o;o>>=1) { ps += __shfl_xor(ps,o); pd += __shfl_xor(pd,o); }
            psv[m*4+q] = ps; pdv[m*4+q] = pd;
            if (wc == 0 && (l&15) == 0) {
                int r = wr*32 + m*16 + (l>>4)*4 + q;
                sm_ps[r] = ps; sm_pd[r] = pd;
            }
        }
    }
    __syncthreads();
    if (wc == 1 && (l&15) == 0) {
        #pragma unroll
        for (int m=0;m<2;m++) {
            #pragma unroll
            for (int q=0;q<4;q++) {
                int r = wr*32 + m*16 + (l>>4)*4 + q;
                int node = n0 + r;
                if (node < N_NODES) {
                    aso2[node] = sm_ps[r] + psv[m*4+q];
                    ado2[node] = sm_pd[r] + pdv[m*4+q];
                }
            }
        }
    }
}

// ---------------- Layer 2: wave-per-node fused softmax + agg + relu + max-pool ----------------
// One 64-lane wave per node, 4 waves/block, zero barriers. e-values broadcast
// via __shfl (register path); each lane gathers ushort2 (cols 2*lane, 2*lane+1).
__global__ __launch_bounds__(256) void k_fagg2(const unsigned short* __restrict__ h2b,
                                               const float* __restrict__ aso,
                                               const float* __restrict__ ado,
                                               const int* __restrict__ cnt,
                                               const int* __restrict__ bucket,
                                               const float* __restrict__ b2,
                                               const int* __restrict__ batch,
                                               float* __restrict__ g) {
    int n    = blockIdx.x*4 + (threadIdx.x >> 6);
    int lane = threadIdx.x & 63;
    if (n >= N_NODES) return;
    int deg = min(cnt[n], CAP);
    const int* brow = bucket + (size_t)n*CAP;
    float adn = ado[n];
    const int j2 = lane*2;
    float acc0 = 0.f, acc1 = 0.f, den = 0.f;

    for (int base = 0; base < deg; base += 64) {
        int m = min(64, deg - base);
        int   sv = 0;
        float ev = 0.f;
        if (lane < m) {
            sv = brow[base + lane];
            float v = aso[sv] + adn;
            v = v > 0.f ? v : 0.2f*v;
            ev = __expf(v);
        }
        int u = 0;
        for (; u + 4 <= m; u += 4) {
            int   sA = __shfl(sv, u),   sB = __shfl(sv, u+1),   sC = __shfl(sv, u+2),   sD = __shfl(sv, u+3);
            float eA = __shfl(ev, u),   eB = __shfl(ev, u+1),   eC = __shfl(ev, u+2),   eD = __shfl(ev, u+3);
            ushort2 hA = *(const ushort2*)(h2b + (size_t)sA*OUT_DIM + j2);
            ushort2 hB = *(const ushort2*)(h2b + (size_t)sB*OUT_DIM + j2);
            ushort2 hC = *(const ushort2*)(h2b + (size_t)sC*OUT_DIM + j2);
            ushort2 hD = *(const ushort2*)(h2b + (size_t)sD*OUT_DIM + j2);
            den  += eA + eB + eC + eD;
            acc0 += bf2f(hA.x)*eA + bf2f(hB.x)*eB + bf2f(hC.x)*eC + bf2f(hD.x)*eD;
            acc1 += bf2f(hA.y)*eA + bf2f(hB.y)*eB + bf2f(hC.y)*eC + bf2f(hD.y)*eD;
        }
        for (; u < m; u++) {
            int   s = __shfl(sv, u);
            float e = __shfl(ev, u);
            ushort2 hv = *(const ushort2*)(h2b + (size_t)s*OUT_DIM + j2);
            den  += e;
            acc0 += bf2f(hv.x)*e;
            acc1 += bf2f(hv.y)*e;
        }
    }
    float iv = 1.f / (den + 1e-16f);
    float v0 = acc0*iv + b2[j2];
    float v1 = acc1*iv + b2[j2+1];
    v0 = v0 > 0.f ? v0 : 0.f;
    v1 = v1 > 0.f ? v1 : 0.f;
    float* grow = g + (size_t)batch[n]*OUT_DIM;
    atomicMax((int*)&grow[j2],   __float_as_int(v0));
    atomicMax((int*)&grow[j2+1], __float_as_int(v1));
}

// out = relu(g @ Wg + bg)   [512,128]x[128,128]
__global__ __launch_bounds__(128) void k_final(const float* __restrict__ g, const float* __restrict__ Wg,
                                               const float* __restrict__ bg, float* __restrict__ out) {
    __shared__ float gl[128];
    int gr = blockIdx.x, j = threadIdx.x;
    gl[j] = g[gr*OUT_DIM + j];
    __syncthreads();
    float acc = 0.f;
    for (int k=0;k<OUT_DIM;k++) acc += gl[k]*Wg[k*OUT_DIM + j];
    float v = acc + bg[j];
    out[gr*OUT_DIM + j] = v>0.f ? v : 0.f;
}

// ---------------- launch ----------------

extern "C" void kernel_launch(void* const* d_in, const int* in_sizes, int n_in,
                              void* d_out, int out_size, void* d_ws, size_t ws_size,
                              hipStream_t stream) {
    const float* x     = (const float*)d_in[0];
    const int*   ei    = (const int*)d_in[1];
    const int*   batch = (const int*)d_in[2];
    const float* W1    = (const float*)d_in[3];
    const float* as1   = (const float*)d_in[4];
    const float* ad1   = (const float*)d_in[5];
    const float* b1    = (const float*)d_in[6];
    const float* W2    = (const float*)d_in[7];
    const float* as2   = (const float*)d_in[8];
    const float* ad2   = (const float*)d_in[9];
    const float* b2    = (const float*)d_in[10];
    const float* Wg    = (const float*)d_in[11];
    const float* bg    = (const float*)d_in[12];
    float* out = (float*)d_out;

    char* ws = (char*)d_ws;
    size_t o = 0;
    auto alloc = [&](size_t bytes) { char* p = ws + o; o = (o + bytes + 255) & ~(size_t)255; return p; };
    unsigned short* xaggb  = (unsigned short*)alloc((size_t)NPAD*960*2);      // [NPAD][10][96] bf16
    unsigned short* h1act  = (unsigned short*)alloc((size_t)NPAD*D2P*2);      // [NPAD][800] bf16
    unsigned short* xbp    = (unsigned short*)alloc((size_t)N_NODES*XK*2);    // [20000][80] bf16
    unsigned short* w1bh   = (unsigned short*)alloc((size_t)HEADS*HOUT*XKP*2);
    unsigned short* w2t    = (unsigned short*)alloc((size_t)OUT_DIM*D2P*2);
    float*          va     = (float*)alloc((size_t)20*F_IN*4);
    float*          aso1   = (float*)alloc((size_t)N_NODES*HEADS*4);
    float*          ado1   = (float*)alloc((size_t)N_NODES*HEADS*4);
    float*          aso2   = (float*)alloc((size_t)N_NODES*4);
    float*          ado2   = (float*)alloc((size_t)N_NODES*4);
    int*            cnt    = (int*)alloc((size_t)N_NODES*4);
    int*            bucket = (int*)alloc((size_t)N_NODES*CAP*4);
    float*          g      = (float*)alloc((size_t)N_GRAPHS*OUT_DIM*4);
    unsigned short* h2b    = (unsigned short*)xaggb;   // xaggb dead after k_gemmh; h2b [20000][128] bf16

    k_prep      <<<(PS6+255)/256, 256, 0, stream>>>(x, W1, as1, ad1, W2, va, xbp, w1bh, w2t, cnt, g);
    k_scat_alpha<<<SCAT_BLOCKS + ALPHA_BLOCKS, 256, 0, stream>>>(ei, cnt, bucket, x, va, aso1, ado1);
    k_fagg1     <<<N_NODES, 128, 0, stream>>>(xbp, aso1, ado1, cnt, bucket, xaggb);
    k_gemmh     <<<dim3(NPAD/64, HEADS), 256, 0, stream>>>(xaggb, w1bh, b1, h1act);
    k_gemm2m    <<<NPAD/64, 256, 0, stream>>>(h1act, w2t, as2, ad2, h2b, aso2, ado2);
    k_fagg2     <<<(N_NODES+3)/4, 256, 0, stream>>>(h2b, aso2, ado2, cnt, bucket, b2, batch, g);
    k_final     <<<N_GRAPHS, 128, 0, stream>>>(g, Wg, bg, out);
}